// Round 9
// baseline (378.124 us; speedup 1.0000x reference)
//
#include <hip/hip_runtime.h>
#include <stdint.h>

// Bloom filter, 2^27 bits, 7 hashes = 7 CONSECUTIVE bits starting at
//   p = ((uint32)v * 2654435761u) & (2^27 - 1)   (wraps mod 2^27)
// Harness dtypes: integer inputs -> int32; bool output -> int32 (0/1).
//
// R17: single persistent megakernel (scatter -> grid-bar -> build+H ->
// grid-bar -> query) + one memset. Dispatches 5 -> 2.
//   R16 post-mortem: insert bundle stuck at 108-118us across SIX configs
//   (threads/buckets/chunk/fusion knobs all flat) -> the bundle is not
//   dominated by kernel inner loops. Remaining invariant: 4 inter-dispatch
//   gaps at ~5-8us each (R11->R15 init-kernel->memset swap moved ~6us).
//   Fusion removes them and gives clean attribution (mega dur = true phase
//   sum; wall - mega = launch overhead).
//   Software grid barrier: 512 blocks x 512 threads, ~39KB LDS, VGPR<=64
//   -> capacity >=3 blocks/CU, need 2 -> all co-resident, no deadlock.
//   Barrier state zeroed by the same memset as gcnt each graph replay.
//   Phase bodies are the measured-best forms verbatim (R15 scatter/build,
//   R11 query, 4x-confirmed signature).

#define NUM_BITS_LOG2 27
#define NUM_BITS (1u << NUM_BITS_LOG2)
#define BIT_MASK (NUM_BITS - 1u)
#define NUM_WORDS (NUM_BITS >> 6)             // 2^21 u64 words = 16 MiB
#define WORD_MASK (NUM_WORDS - 1u)
#define PRIME 2654435761u
#define H_WORDS (NUM_WORDS >> 2)              // 2^19 u64 H-words = 4 MiB

#define NBUCKETS 512
#define BKT_SHIFT (NUM_BITS_LOG2 - 9)         // 18: region = 2^18 bits
#define REGION_WORDS (1u << (BKT_SHIFT - 6))  // 4096 u64 = 32 KiB
#define H_WORDS_PER_REGION (REGION_WORDS / 4) // 1024 u64 H-words per region
#define CAP 8688u                             // per-bucket cap (mean 7813 + 9.9 sigma)
#define CHUNK 8192u                           // values per sorted chunk (32 KiB LDS)
#define GRID_A 512                            // megakernel blocks (== NBUCKETS)

typedef int vint4 __attribute__((ext_vector_type(4)));
typedef unsigned long long vull2 __attribute__((ext_vector_type(2)));

// ---------------- workspace layout (bytes) ----------------
// [0, 16777216)            bits   u64 x 2^21   (16 MiB)
// [16777216, 20971520)     H      u64 x 2^19   (4 MiB)
// [20971520, 38764544)     lists  u32 x 512*8688
// [38764544, 38766592)     gcnt   u32 x 512
// [38766592, 38766600)     bar    u32 x 2 (count, gen)
#define WS_H_ONLY 20971520ull
#define WS_FULL   38766656ull

// ---------- device-scope grid barrier (all blocks co-resident by design) ----------
__device__ __forceinline__ void grid_bar(uint32_t* __restrict__ bar) {
    __syncthreads();
    if (threadIdx.x == 0) {
        __threadfence();                                       // release all block writes
        uint32_t g = __hip_atomic_load(&bar[1], __ATOMIC_RELAXED, __HIP_MEMORY_SCOPE_AGENT);
        uint32_t a = __hip_atomic_fetch_add(&bar[0], 1u, __ATOMIC_ACQ_REL,
                                            __HIP_MEMORY_SCOPE_AGENT);
        if (a + 1u == (uint32_t)GRID_A) {
            __hip_atomic_store(&bar[0], 0u, __ATOMIC_RELAXED, __HIP_MEMORY_SCOPE_AGENT);
            __hip_atomic_fetch_add(&bar[1], 1u, __ATOMIC_RELEASE, __HIP_MEMORY_SCOPE_AGENT);
        } else {
            while (__hip_atomic_load(&bar[1], __ATOMIC_ACQUIRE,
                                     __HIP_MEMORY_SCOPE_AGENT) == g)
                __builtin_amdgcn_s_sleep(16);
        }
        __threadfence();                                       // acquire side
    }
    __syncthreads();
}

// ---------- helpers ----------
__device__ __forceinline__ void set_window(unsigned long long* bm, uint32_t p, uint32_t b) {
    int d = (int)((p - (b << BKT_SHIFT)) & BIT_MASK);
    if (d >= (1 << 26)) d -= (1 << 27);                 // dup from prev region / wrap
    if (d < -6 || d >= (1 << BKT_SHIFT)) return;        // safety guard
    if (d < 0) {
        atomicOr(&bm[0], 0x7Full >> (uint32_t)(-d));
    } else {
        uint32_t w = (uint32_t)d >> 6, s = (uint32_t)d & 63u;
        atomicOr(&bm[w], 0x7Full << s);
        if (s > 57u) atomicOr(&bm[w + 1], 0x7Full >> (64u - s));  // slack word absorbs
    }
}

// 16 nibble-AND bits of one u64 fine word, compacted to low 16 bits
__device__ __forceinline__ unsigned long long nib16(unsigned long long a) {
    unsigned long long t = a & (a >> 1);
    unsigned long long u = t & (t >> 2);                // bit 4k = AND of bits 4k..4k+3
    u &= 0x1111111111111111ull;
    u |= u >> 3;  u &= 0x0303030303030303ull;
    u |= u >> 6;  u &= 0x000F000F000F000Full;
    u |= u >> 12; u &= 0x000000FF000000FFull;
    u |= u >> 24; return u & 0xFFFFull;
}

__device__ __forceinline__ int query_one_branchy(uint32_t v,
                                                 const unsigned long long* __restrict__ bits) {
    uint32_t p = (v * PRIME) & BIT_MASK;
    uint32_t w = p >> 6, s = p & 63u;
    unsigned long long lo = bits[w];
    unsigned long long win;
    if (s <= 57u) win = lo >> s;
    else win = (lo >> s) | (bits[(w + 1u) & WORD_MASK] << (64u - s));
    return ((win & 0x7Full) == 0x7Full) ? 1 : 0;
}

// ---------- the megakernel ----------
__global__ __launch_bounds__(512) void bloom_fused_kernel(
    const int* __restrict__ add_vals, int n_add,
    const int* __restrict__ qvals, int n_query,
    uint32_t* __restrict__ lists, uint32_t* __restrict__ gcnt,
    unsigned long long* __restrict__ bits, unsigned long long* __restrict__ H,
    int* __restrict__ out, uint32_t* __restrict__ bar)
{
    __shared__ union {
        struct {
            uint32_t hist[NBUCKETS];
            uint32_t cur[NBUCKETS];
            uint32_t gdelta[NBUCKETS];
            uint32_t wsum[8];
            uint32_t wexc[8];
            uint32_t total;
            uint32_t sortbuf[CHUNK];
        } a;                                            // scatter phase (~38.2 KiB)
        struct {
            unsigned long long bm[REGION_WORDS + 1];
        } b;                                            // build phase (32.8 KiB)
    } sh;

    const uint32_t tid = threadIdx.x;
    const uint32_t lane = tid & 63u;
    const uint32_t wv = tid >> 6;

    // ================= phase A: chunk counting-sort scatter (R15 body) =========
    {
        const uint32_t un = (uint32_t)n_add;
        const uint32_t nchunks = (un + CHUNK - 1u) / CHUNK;
        for (uint32_t c = blockIdx.x; c < nchunks; c += gridDim.x) {
            const uint32_t base = c * CHUNK;
            const bool full = (base + CHUNK <= un);

            sh.a.hist[tid] = 0u;
            __syncthreads();

            vint4 vv[4];                                // 16 values/thread
            if (full) {
                const vint4* src = (const vint4*)(add_vals + base);
                #pragma unroll
                for (int k = 0; k < 4; ++k) vv[k] = src[(uint32_t)k * 512u + tid];
                #pragma unroll
                for (int k = 0; k < 4; ++k) {
                    #pragma unroll
                    for (int j = 0; j < 4; ++j) {
                        uint32_t p = ((uint32_t)vv[k][j] * PRIME) & BIT_MASK;
                        uint32_t b1 = p >> BKT_SHIFT;
                        atomicAdd(&sh.a.hist[b1], 1u);
                        uint32_t b2 = ((p + 6u) & BIT_MASK) >> BKT_SHIFT;
                        if (b2 != b1) {                 // ~92 total in whole input
                            uint32_t s2 = atomicAdd(&gcnt[b2], 1u);
                            if (s2 < CAP) lists[b2 * CAP + s2] = p;
                        }
                    }
                }
            } else {
                #pragma unroll
                for (int k = 0; k < 16; ++k) {
                    uint32_t idx = base + (uint32_t)k * 512u + tid;
                    if (idx < un) {
                        uint32_t p = ((uint32_t)add_vals[idx] * PRIME) & BIT_MASK;
                        uint32_t b1 = p >> BKT_SHIFT;
                        atomicAdd(&sh.a.hist[b1], 1u);
                        uint32_t b2 = ((p + 6u) & BIT_MASK) >> BKT_SHIFT;
                        if (b2 != b1) {
                            uint32_t s2 = atomicAdd(&gcnt[b2], 1u);
                            if (s2 < CAP) lists[b2 * CAP + s2] = p;
                        }
                    }
                }
            }
            __syncthreads();

            // wave-shuffle inclusive scan over 512 bins (1 bin/thread)
            const uint32_t c0 = sh.a.hist[tid];
            uint32_t x = c0;
            #pragma unroll
            for (uint32_t d = 1; d < 64; d <<= 1) {
                uint32_t y = __shfl_up(x, d, 64);
                if (lane >= d) x += y;
            }
            if (lane == 63u) sh.a.wsum[wv] = x;
            __syncthreads();
            if (wv == 0) {
                uint32_t t8 = (lane < 8u) ? sh.a.wsum[lane] : 0u;
                #pragma unroll
                for (uint32_t d = 1; d < 8; d <<= 1) {
                    uint32_t y = __shfl_up(t8, d, 64);
                    if (lane >= d) t8 += y;
                }
                if (lane < 8u) sh.a.wexc[lane] = t8 - sh.a.wsum[lane];
            }
            __syncthreads();
            const uint32_t inc = x + sh.a.wexc[wv];
            const uint32_t lb = inc - c0;
            if (tid == NBUCKETS - 1) sh.a.total = inc;

            uint32_t go = c0 ? atomicAdd(&gcnt[tid], c0) : 0u;
            sh.a.cur[tid] = lb;
            sh.a.gdelta[tid] = tid * CAP + go - lb;     // u32 wraparound exact
            __syncthreads();

            if (full) {
                #pragma unroll
                for (int k = 0; k < 4; ++k) {
                    #pragma unroll
                    for (int j = 0; j < 4; ++j) {
                        uint32_t p = ((uint32_t)vv[k][j] * PRIME) & BIT_MASK;
                        uint32_t b1 = p >> BKT_SHIFT;
                        uint32_t s = atomicAdd(&sh.a.cur[b1], 1u);
                        sh.a.sortbuf[s] = p;
                    }
                }
            } else {
                #pragma unroll
                for (int k = 0; k < 16; ++k) {
                    uint32_t idx = base + (uint32_t)k * 512u + tid;
                    if (idx < un) {
                        uint32_t p = ((uint32_t)add_vals[idx] * PRIME) & BIT_MASK;
                        uint32_t b1 = p >> BKT_SHIFT;
                        uint32_t s = atomicAdd(&sh.a.cur[b1], 1u);
                        sh.a.sortbuf[s] = p;
                    }
                }
            }
            __syncthreads();

            const uint32_t total = sh.a.total;
            for (uint32_t i = tid; i < total; i += 512u) {
                uint32_t p = sh.a.sortbuf[i];
                uint32_t b = p >> BKT_SHIFT;
                uint32_t dst = sh.a.gdelta[b] + i;
                if (dst - b * CAP < CAP) lists[dst] = p;
            }
            __syncthreads();
        }
    }

    grid_bar(bar);

    // ================= phase B: build region bitmap + fused H (R15 body) =======
    {
        const uint32_t b = blockIdx.x;                  // gridDim == NBUCKETS
        for (uint32_t i = tid; i < REGION_WORDS + 1; i += 512) sh.b.bm[i] = 0ull;
        __syncthreads();

        const uint32_t m = min(gcnt[b], CAP);
        const uint32_t base = b * CAP;
        for (uint32_t i = tid; i < m; i += 512) set_window(sh.b.bm, lists[base + i], b);
        __syncthreads();

        const uint32_t out_base = b * REGION_WORDS;
        for (uint32_t i = tid; i < REGION_WORDS / 2; i += 512) {
            vull2 w; w[0] = sh.b.bm[i * 2]; w[1] = sh.b.bm[i * 2 + 1];
            *((vull2*)(bits + out_base) + i) = w;       // temporal: warm L3 for query
        }
        const uint32_t h_base = b * H_WORDS_PER_REGION;
        for (uint32_t i = tid; i < H_WORDS_PER_REGION; i += 512) {
            unsigned long long hw = nib16(sh.b.bm[i * 4])
                                  | (nib16(sh.b.bm[i * 4 + 1]) << 16)
                                  | (nib16(sh.b.bm[i * 4 + 2]) << 32)
                                  | (nib16(sh.b.bm[i * 4 + 3]) << 48);
            H[h_base + i] = hw;                         // temporal: lives in L2
        }
    }

    grid_bar(bar);

    // ================= phase C: query (R11 body, grid-strided) =================
    {
        const uint32_t* H32 = (const uint32_t*)H;
        const uint32_t nthreads = gridDim.x * 512u;
        const uint32_t items = ((uint32_t)n_query + 7u) / 8u;
        for (uint32_t it = blockIdx.x * 512u + tid; it < items; it += nthreads) {
            int base = (int)(it * 8u);
            if (base + 7 < n_query) {
                vint4 v0 = __builtin_nontemporal_load((const vint4*)(qvals + base));
                vint4 v1 = __builtin_nontemporal_load((const vint4*)(qvals + base + 4));
                uint32_t p[8], pass[8];
                #pragma unroll
                for (int j = 0; j < 4; ++j) {
                    p[j]     = ((uint32_t)v0[j] * PRIME) & BIT_MASK;
                    p[j + 4] = ((uint32_t)v1[j] * PRIME) & BIT_MASK;
                }
                #pragma unroll
                for (int j = 0; j < 8; ++j) {           // 8 independent L2-hit H probes
                    uint32_t m = ((p[j] + 3u) & BIT_MASK) >> 2;
                    pass[j] = (H32[m >> 5] >> (m & 31u)) & 1u;
                }
                unsigned long long lo[8], hi[8];
                uint32_t w[8], s[8];
                #pragma unroll
                for (int j = 0; j < 8; ++j) {           // masked fine gathers, CACHED
                    w[j] = p[j] >> 6; s[j] = p[j] & 63u;
                    lo[j] = 0ull; hi[j] = 0ull;
                    if (pass[j]) lo[j] = bits[w[j]];
                }
                #pragma unroll
                for (int j = 0; j < 8; ++j) {           // masked hi gathers, CACHED
                    if (pass[j] && s[j] > 57u)
                        hi[j] = bits[(w[j] + 1u) & WORD_MASK];
                }
                vint4 r0, r1;
                #pragma unroll
                for (int j = 0; j < 8; ++j) {
                    unsigned long long win = (lo[j] >> s[j]) | ((hi[j] << 1) << (63u - s[j]));
                    int r = ((win & 0x7Full) == 0x7Full) ? 1 : 0;
                    if (j < 4) r0[j] = r; else r1[j - 4] = r;
                }
                __builtin_nontemporal_store(r0, (vint4*)(out + base));
                __builtin_nontemporal_store(r1, (vint4*)(out + base + 4));
            } else {
                for (int j = base; j < n_query; ++j)
                    out[j] = query_one_branchy((uint32_t)qvals[j], bits);
            }
        }
    }
}

// ---------- fallback path (small ws): global-atomic insert + plain query ----------
__global__ __launch_bounds__(256) void zero_bits_kernel(vull2* __restrict__ bits, int n2) {
    int i = blockIdx.x * 256 + threadIdx.x;
    if (i < n2) { vull2 z = {0ull, 0ull}; __builtin_nontemporal_store(z, &bits[i]); }
}

__device__ __forceinline__ void insert_one_atomic(uint32_t v,
                                                  unsigned long long* __restrict__ bits) {
    uint32_t p = (v * PRIME) & BIT_MASK;
    uint32_t w = p >> 6, s = p & 63u;
    atomicOr(bits + w, 0x7Full << s);
    if (s > 57u) atomicOr(bits + ((w + 1u) & WORD_MASK), 0x7Full >> (64u - s));
}

__global__ __launch_bounds__(256) void insert_atomic_kernel(const int* __restrict__ vals, int n,
                                                            unsigned long long* __restrict__ bits) {
    int t = blockIdx.x * 256 + threadIdx.x;
    int base = t * 4;
    if (base + 3 < n) {
        vint4 v = __builtin_nontemporal_load((const vint4*)vals + t);
        insert_one_atomic((uint32_t)v.x, bits);
        insert_one_atomic((uint32_t)v.y, bits);
        insert_one_atomic((uint32_t)v.z, bits);
        insert_one_atomic((uint32_t)v.w, bits);
    } else {
        for (int j = base; j < n; ++j) insert_one_atomic((uint32_t)vals[j], bits);
    }
}

__global__ __launch_bounds__(256) void build_h_kernel(
    const unsigned long long* __restrict__ bits, unsigned long long* __restrict__ H)
{
    uint32_t i = blockIdx.x * 256 + threadIdx.x;        // [0, 2^19), grid exact
    const vull2* b2 = (const vull2*)bits + (size_t)i * 2;
    vull2 a = b2[0];
    vull2 b = b2[1];
    unsigned long long hw = nib16(a[0])
                          | (nib16(a[1]) << 16)
                          | (nib16(b[0]) << 32)
                          | (nib16(b[1]) << 48);
    H[i] = hw;
}

__global__ __launch_bounds__(256) void query_kernelH(
    const int* __restrict__ vals, int n,
    const unsigned long long* __restrict__ bits,
    const uint32_t* __restrict__ H32, int* __restrict__ out)
{
    int t = blockIdx.x * 256 + threadIdx.x;
    int base = t * 8;
    if (base + 7 < n) {
        vint4 v0 = __builtin_nontemporal_load((const vint4*)(vals + base));
        vint4 v1 = __builtin_nontemporal_load((const vint4*)(vals + base + 4));
        uint32_t p[8], pass[8];
        #pragma unroll
        for (int j = 0; j < 4; ++j) {
            p[j]     = ((uint32_t)v0[j] * PRIME) & BIT_MASK;
            p[j + 4] = ((uint32_t)v1[j] * PRIME) & BIT_MASK;
        }
        #pragma unroll
        for (int j = 0; j < 8; ++j) {
            uint32_t m = ((p[j] + 3u) & BIT_MASK) >> 2;
            pass[j] = (H32[m >> 5] >> (m & 31u)) & 1u;
        }
        unsigned long long lo[8], hi[8];
        uint32_t w[8], s[8];
        #pragma unroll
        for (int j = 0; j < 8; ++j) {
            w[j] = p[j] >> 6; s[j] = p[j] & 63u;
            lo[j] = 0ull; hi[j] = 0ull;
            if (pass[j]) lo[j] = bits[w[j]];
        }
        #pragma unroll
        for (int j = 0; j < 8; ++j) {
            if (pass[j] && s[j] > 57u)
                hi[j] = bits[(w[j] + 1u) & WORD_MASK];
        }
        vint4 r0, r1;
        #pragma unroll
        for (int j = 0; j < 8; ++j) {
            unsigned long long win = (lo[j] >> s[j]) | ((hi[j] << 1) << (63u - s[j]));
            int r = ((win & 0x7Full) == 0x7Full) ? 1 : 0;
            if (j < 4) r0[j] = r; else r1[j - 4] = r;
        }
        __builtin_nontemporal_store(r0, (vint4*)(out + base));
        __builtin_nontemporal_store(r1, (vint4*)(out + base + 4));
    } else {
        for (int j = base; j < n; ++j)
            out[j] = query_one_branchy((uint32_t)vals[j], bits);
    }
}

__global__ __launch_bounds__(256) void query_kernel8(
    const int* __restrict__ vals, int n,
    const unsigned long long* __restrict__ bits, int* __restrict__ out)
{
    int t = blockIdx.x * 256 + threadIdx.x;
    int base = t * 8;
    if (base + 7 < n) {
        vint4 v0 = __builtin_nontemporal_load((const vint4*)(vals + base));
        vint4 v1 = __builtin_nontemporal_load((const vint4*)(vals + base + 4));
        vint4 r0, r1;
        #pragma unroll
        for (int j = 0; j < 8; ++j) {
            uint32_t v = (uint32_t)(j < 4 ? v0[j] : v1[j - 4]);
            int r = query_one_branchy(v, bits);
            if (j < 4) r0[j] = r; else r1[j - 4] = r;
        }
        __builtin_nontemporal_store(r0, (vint4*)(out + base));
        __builtin_nontemporal_store(r1, (vint4*)(out + base + 4));
    } else {
        for (int j = base; j < n; ++j)
            out[j] = query_one_branchy((uint32_t)vals[j], bits);
    }
}

extern "C" void kernel_launch(void* const* d_in, const int* in_sizes, int n_in,
                              void* d_out, int out_size, void* d_ws, size_t ws_size,
                              hipStream_t stream) {
    const int* add_values   = (const int*)d_in[0];
    const int* query_values = (const int*)d_in[1];
    const int n_add   = in_sizes[0];   // 4,000,000
    const int n_query = in_sizes[1];   // 8,000,000
    int* out = (int*)d_out;

    uint8_t* ws = (uint8_t*)d_ws;
    unsigned long long* bits = (unsigned long long*)ws;
    unsigned long long* H    = (unsigned long long*)(ws + 16777216);
    uint32_t* lists = (uint32_t*)(ws + 20971520);
    uint32_t* gcnt  = (uint32_t*)(ws + 38764544);
    uint32_t* bar   = (uint32_t*)(ws + 38766592);

    const int threads8 = (n_query + 7) / 8;

    if (ws_size >= WS_FULL) {
        // zero gcnt (2048B) + barrier state (8B) in one memset
        hipMemsetAsync(gcnt, 0, 2048 + 64, stream);
        bloom_fused_kernel<<<GRID_A, 512, 0, stream>>>(
            add_values, n_add, query_values, n_query,
            lists, gcnt, bits, H, out, bar);
    } else if (ws_size >= WS_H_ONLY) {
        const int n2 = NUM_WORDS / 2;
        zero_bits_kernel<<<(n2 + 255) / 256, 256, 0, stream>>>((vull2*)bits, n2);
        const int threads4 = (n_add + 3) / 4;
        insert_atomic_kernel<<<(threads4 + 255) / 256, 256, 0, stream>>>(
            add_values, n_add, bits);
        build_h_kernel<<<H_WORDS / 256, 256, 0, stream>>>(bits, H);
        query_kernelH<<<(threads8 + 255) / 256, 256, 0, stream>>>(
            query_values, n_query, bits, (const uint32_t*)H, out);
    } else {
        const int n2 = NUM_WORDS / 2;
        zero_bits_kernel<<<(n2 + 255) / 256, 256, 0, stream>>>((vull2*)bits, n2);
        const int threads4 = (n_add + 3) / 4;
        insert_atomic_kernel<<<(threads4 + 255) / 256, 256, 0, stream>>>(
            add_values, n_add, bits);
        query_kernel8<<<(threads8 + 255) / 256, 256, 0, stream>>>(
            query_values, n_query, bits, out);
    }
}

// Round 10
// 175.397 us; speedup vs baseline: 2.1558x; 2.1558x over previous
//
#include <hip/hip_runtime.h>
#include <stdint.h>

// Bloom filter, 2^27 bits, 7 hashes = 7 CONSECUTIVE bits starting at
//   p = ((uint32)v * 2654435761u) & (2^27 - 1)   (wraps mod 2^27)
// Harness dtypes: integer inputs -> int32; bool output -> int32 (0/1).
//
// R18: revert to R15 (179.5us best) + build_bitmap at 1024 threads.
//   R17 post-mortem: megakernel VGPR=32 (launch_bounds w/o waves hint) ->
//   scratch spill in every phase, 320us. Byproduct measurement: solving
//   R17 (F+1gap=58) against R9 (F+4gaps=63) gives per-dispatch gap ~2us,
//   fixed harness overhead F ~56us -> fusion was never worth >6us. Dead end.
//   Budget at R15: F 56 + query 68 (4x confirmed) + scatter+build ~51.
//   This round's single lever: build at 1024 thr (512 blocks x 16 waves,
//   2/CU -> 32 waves/CU, was 16) -- the one untested occupancy cell in the
//   insert bundle; per-block serial depth halves, bodies otherwise verbatim.

#define NUM_BITS_LOG2 27
#define NUM_BITS (1u << NUM_BITS_LOG2)
#define BIT_MASK (NUM_BITS - 1u)
#define NUM_WORDS (NUM_BITS >> 6)             // 2^21 u64 words = 16 MiB
#define WORD_MASK (NUM_WORDS - 1u)
#define PRIME 2654435761u
#define H_WORDS (NUM_WORDS >> 2)              // 2^19 u64 H-words = 4 MiB

#define NBUCKETS 512
#define BKT_SHIFT (NUM_BITS_LOG2 - 9)         // 18: region = 2^18 bits
#define REGION_WORDS (1u << (BKT_SHIFT - 6))  // 4096 u64 = 32 KiB
#define H_WORDS_PER_REGION (REGION_WORDS / 4) // 1024 u64 H-words per region
#define CAP 8688u                             // per-bucket cap (mean 7813 + 9.9 sigma)
#define CHUNK 8192u                           // values per sorted chunk (32 KiB LDS)

typedef int vint4 __attribute__((ext_vector_type(4)));
typedef unsigned long long vull2 __attribute__((ext_vector_type(2)));

// ---------------- workspace layout (bytes) ----------------
// [0, 16777216)            bits   u64 x 2^21   (16 MiB)
// [16777216, 20971520)     H      u64 x 2^19   (4 MiB)
// [20971520, 38764544)     lists  u32 x 512*8688
// [38764544, 38766592)     gcnt   u32 x 512
#define WS_H_ONLY 20971520ull
#define WS_FULL   38766592ull

// ---------- phase A: per-chunk LDS counting sort -> coalesced list flush ----------
// 512 threads/block, 1 bin/thread, wave-shuffle scan (3 syncs), 16 vals/thread.
__global__ __launch_bounds__(512) void scatter_kernel(
    const int* __restrict__ vals, int n,
    uint32_t* __restrict__ lists, uint32_t* __restrict__ gcnt)
{
    __shared__ uint32_t hist[NBUCKETS];
    __shared__ uint32_t cur[NBUCKETS];     // local slot cursors
    __shared__ uint32_t gdelta[NBUCKETS];  // slot i -> global list index (u32 wrap ok)
    __shared__ uint32_t wsum[8];
    __shared__ uint32_t wexc[8];
    __shared__ uint32_t total_s;
    __shared__ uint32_t sortbuf[CHUNK];
    const uint32_t tid = threadIdx.x;
    const uint32_t lane = tid & 63u;
    const uint32_t wv = tid >> 6;
    const uint32_t un = (uint32_t)n;
    const uint32_t nchunks = (un + CHUNK - 1u) / CHUNK;

    for (uint32_t c = blockIdx.x; c < nchunks; c += gridDim.x) {
        const uint32_t base = c * CHUNK;
        const bool full = (base + CHUNK <= un);

        hist[tid] = 0u;
        __syncthreads();

        // ---- pass 1: histogram (+ direct write of rare straddle dups) ----
        vint4 vv[4];                                    // 16 values/thread
        if (full) {
            const vint4* src = (const vint4*)(vals + base);
            #pragma unroll
            for (int k = 0; k < 4; ++k) vv[k] = src[(uint32_t)k * 512u + tid];
            #pragma unroll
            for (int k = 0; k < 4; ++k) {
                #pragma unroll
                for (int j = 0; j < 4; ++j) {
                    uint32_t p = ((uint32_t)vv[k][j] * PRIME) & BIT_MASK;
                    uint32_t b1 = p >> BKT_SHIFT;
                    atomicAdd(&hist[b1], 1u);
                    uint32_t b2 = ((p + 6u) & BIT_MASK) >> BKT_SHIFT;
                    if (b2 != b1) {                     // ~92 total in whole input
                        uint32_t s2 = atomicAdd(&gcnt[b2], 1u);
                        if (s2 < CAP) lists[b2 * CAP + s2] = p;
                    }
                }
            }
        } else {
            #pragma unroll
            for (int k = 0; k < 16; ++k) {
                uint32_t idx = base + (uint32_t)k * 512u + tid;
                if (idx < un) {
                    uint32_t p = ((uint32_t)vals[idx] * PRIME) & BIT_MASK;
                    uint32_t b1 = p >> BKT_SHIFT;
                    atomicAdd(&hist[b1], 1u);
                    uint32_t b2 = ((p + 6u) & BIT_MASK) >> BKT_SHIFT;
                    if (b2 != b1) {
                        uint32_t s2 = atomicAdd(&gcnt[b2], 1u);
                        if (s2 < CAP) lists[b2 * CAP + s2] = p;
                    }
                }
            }
        }
        __syncthreads();

        // ---- wave-shuffle inclusive scan over 512 bins ----
        const uint32_t c0 = hist[tid];
        uint32_t x = c0;
        #pragma unroll
        for (uint32_t d = 1; d < 64; d <<= 1) {
            uint32_t y = __shfl_up(x, d, 64);
            if (lane >= d) x += y;
        }
        if (lane == 63u) wsum[wv] = x;
        __syncthreads();
        if (wv == 0) {
            uint32_t t8 = (lane < 8u) ? wsum[lane] : 0u;
            #pragma unroll
            for (uint32_t d = 1; d < 8; d <<= 1) {
                uint32_t y = __shfl_up(t8, d, 64);
                if (lane >= d) t8 += y;
            }
            if (lane < 8u) wexc[lane] = t8 - wsum[lane];   // exclusive wave offset
        }
        __syncthreads();
        const uint32_t inc = x + wexc[wv];                 // inclusive scan of bin tid
        const uint32_t lb = inc - c0;                      // exclusive (local base)
        if (tid == NBUCKETS - 1) total_s = inc;

        // ---- reserve global chunk; slot->global mapping ----
        uint32_t go = c0 ? atomicAdd(&gcnt[tid], c0) : 0u;
        cur[tid] = lb;
        gdelta[tid] = tid * CAP + go - lb;                 // u32 wraparound exact
        __syncthreads();

        // ---- pass 2: counting-sort p values into LDS ----
        if (full) {
            #pragma unroll
            for (int k = 0; k < 4; ++k) {
                #pragma unroll
                for (int j = 0; j < 4; ++j) {
                    uint32_t p = ((uint32_t)vv[k][j] * PRIME) & BIT_MASK;
                    uint32_t b1 = p >> BKT_SHIFT;
                    uint32_t s = atomicAdd(&cur[b1], 1u);
                    sortbuf[s] = p;
                }
            }
        } else {
            #pragma unroll
            for (int k = 0; k < 16; ++k) {
                uint32_t idx = base + (uint32_t)k * 512u + tid;
                if (idx < un) {
                    uint32_t p = ((uint32_t)vals[idx] * PRIME) & BIT_MASK;
                    uint32_t b1 = p >> BKT_SHIFT;
                    uint32_t s = atomicAdd(&cur[b1], 1u);
                    sortbuf[s] = p;
                }
            }
        }
        __syncthreads();

        // ---- flush: slots grouped by ascending bucket -> coalesced run writes ----
        const uint32_t total = total_s;
        for (uint32_t i = tid; i < total; i += 512u) {
            uint32_t p = sortbuf[i];
            uint32_t b = p >> BKT_SHIFT;
            uint32_t dst = gdelta[b] + i;
            if (dst - b * CAP < CAP) lists[dst] = p;    // clamp: statistically unreachable
        }
        __syncthreads();                                // protect LDS reuse next iter
    }
}

// ---------- phase B: build region bitmap in LDS, emit bits + H ----------
__device__ __forceinline__ void set_window(unsigned long long* bm, uint32_t p, uint32_t b) {
    int d = (int)((p - (b << BKT_SHIFT)) & BIT_MASK);
    if (d >= (1 << 26)) d -= (1 << 27);                 // dup from prev region / wrap
    if (d < -6 || d >= (1 << BKT_SHIFT)) return;        // safety guard
    if (d < 0) {
        atomicOr(&bm[0], 0x7Full >> (uint32_t)(-d));
    } else {
        uint32_t w = (uint32_t)d >> 6, s = (uint32_t)d & 63u;
        atomicOr(&bm[w], 0x7Full << s);
        if (s > 57u) atomicOr(&bm[w + 1], 0x7Full >> (64u - s));  // slack word absorbs
    }
}

// 16 nibble-AND bits of one u64 fine word, compacted to low 16 bits
__device__ __forceinline__ unsigned long long nib16(unsigned long long a) {
    unsigned long long t = a & (a >> 1);
    unsigned long long u = t & (t >> 2);                // bit 4k = AND of bits 4k..4k+3
    u &= 0x1111111111111111ull;
    u |= u >> 3;  u &= 0x0303030303030303ull;
    u |= u >> 6;  u &= 0x000F000F000F000Full;
    u |= u >> 12; u &= 0x000000FF000000FFull;
    u |= u >> 24; return u & 0xFFFFull;
}

// 512 blocks (one per bucket), 1024 threads (16 waves): 2 blocks/CU ->
// 32 waves/CU (R15 had 16). Per-block serial depth halves; body verbatim.
__global__ __launch_bounds__(1024) void build_bitmap_kernel(
    const uint32_t* __restrict__ lists, const uint32_t* __restrict__ gcnt,
    unsigned long long* __restrict__ bits, unsigned long long* __restrict__ H)
{
    __shared__ unsigned long long bm[REGION_WORDS + 1];
    const uint32_t b = blockIdx.x, tid = threadIdx.x;
    for (uint32_t i = tid; i < REGION_WORDS + 1; i += 1024) bm[i] = 0ull;
    __syncthreads();

    // dense bucket list -> fully coalesced cooperative read
    const uint32_t m = min(gcnt[b], CAP);
    const uint32_t base = b * CAP;
    for (uint32_t i = tid; i < m; i += 1024) set_window(bm, lists[base + i], b);
    __syncthreads();

    const uint32_t out_base = b * REGION_WORDS;
    for (uint32_t i = tid; i < REGION_WORDS / 2; i += 1024) {
        vull2 w; w[0] = bm[i * 2]; w[1] = bm[i * 2 + 1];
        *((vull2*)(bits + out_base) + i) = w;           // temporal: warm L3 for query
    }
    const uint32_t h_base = b * H_WORDS_PER_REGION;
    for (uint32_t i = tid; i < H_WORDS_PER_REGION; i += 1024) {
        unsigned long long hw = nib16(bm[i * 4])
                              | (nib16(bm[i * 4 + 1]) << 16)
                              | (nib16(bm[i * 4 + 2]) << 32)
                              | (nib16(bm[i * 4 + 3]) << 48);
        H[h_base + i] = hw;                 // temporal: H wants to live in L2
    }
}

// ---------- query: H pre-filter (L2-resident), fine bitmap only on pass ----------
__device__ __forceinline__ int query_one_branchy(uint32_t v,
                                                 const unsigned long long* __restrict__ bits) {
    uint32_t p = (v * PRIME) & BIT_MASK;
    uint32_t w = p >> 6, s = p & 63u;
    unsigned long long lo = bits[w];
    unsigned long long win;
    if (s <= 57u) win = lo >> s;
    else win = (lo >> s) | (bits[(w + 1u) & WORD_MASK] << (64u - s));
    return ((win & 0x7Full) == 0x7Full) ? 1 : 0;
}

// R11's proven config (4x confirmed): 8 queries/thread, nibble filter (4MB,
// L2-resident), cached fine gathers, NT streaming I/O. 68us / VGPR 40.
__global__ __launch_bounds__(256) void query_kernelH(
    const int* __restrict__ vals, int n,
    const unsigned long long* __restrict__ bits,
    const uint32_t* __restrict__ H32, int* __restrict__ out)
{
    int t = blockIdx.x * 256 + threadIdx.x;
    int base = t * 8;
    if (base + 7 < n) {
        vint4 v0 = __builtin_nontemporal_load((const vint4*)(vals + base));
        vint4 v1 = __builtin_nontemporal_load((const vint4*)(vals + base + 4));
        uint32_t p[8], pass[8];
        #pragma unroll
        for (int j = 0; j < 4; ++j) {
            p[j]     = ((uint32_t)v0[j] * PRIME) & BIT_MASK;
            p[j + 4] = ((uint32_t)v1[j] * PRIME) & BIT_MASK;
        }
        #pragma unroll
        for (int j = 0; j < 8; ++j) {           // 8 independent L2-hit H probes
            uint32_t m = ((p[j] + 3u) & BIT_MASK) >> 2;
            pass[j] = (H32[m >> 5] >> (m & 31u)) & 1u;
        }
        unsigned long long lo[8], hi[8];
        uint32_t w[8], s[8];
        #pragma unroll
        for (int j = 0; j < 8; ++j) {           // masked fine gathers (~13% lanes), CACHED
            w[j] = p[j] >> 6; s[j] = p[j] & 63u;
            lo[j] = 0ull; hi[j] = 0ull;
            if (pass[j]) lo[j] = bits[w[j]];
        }
        #pragma unroll
        for (int j = 0; j < 8; ++j) {           // masked hi gathers (~1.1% lanes), CACHED
            if (pass[j] && s[j] > 57u)
                hi[j] = bits[(w[j] + 1u) & WORD_MASK];
        }
        vint4 r0, r1;
        #pragma unroll
        for (int j = 0; j < 8; ++j) {
            unsigned long long win = (lo[j] >> s[j]) | ((hi[j] << 1) << (63u - s[j]));
            int r = ((win & 0x7Full) == 0x7Full) ? 1 : 0;
            if (j < 4) r0[j] = r; else r1[j - 4] = r;
        }
        __builtin_nontemporal_store(r0, (vint4*)(out + base));
        __builtin_nontemporal_store(r1, (vint4*)(out + base + 4));
    } else {
        for (int j = base; j < n; ++j)
            out[j] = query_one_branchy((uint32_t)vals[j], bits);
    }
}

// ---------- fallback path (small ws): global-atomic insert + plain query ----------
__global__ __launch_bounds__(256) void zero_bits_kernel(vull2* __restrict__ bits, int n2) {
    int i = blockIdx.x * 256 + threadIdx.x;
    if (i < n2) { vull2 z = {0ull, 0ull}; __builtin_nontemporal_store(z, &bits[i]); }
}

__device__ __forceinline__ void insert_one_atomic(uint32_t v,
                                                  unsigned long long* __restrict__ bits) {
    uint32_t p = (v * PRIME) & BIT_MASK;
    uint32_t w = p >> 6, s = p & 63u;
    atomicOr(bits + w, 0x7Full << s);
    if (s > 57u) atomicOr(bits + ((w + 1u) & WORD_MASK), 0x7Full >> (64u - s));
}

__global__ __launch_bounds__(256) void insert_atomic_kernel(const int* __restrict__ vals, int n,
                                                            unsigned long long* __restrict__ bits) {
    int t = blockIdx.x * 256 + threadIdx.x;
    int base = t * 4;
    if (base + 3 < n) {
        vint4 v = __builtin_nontemporal_load((const vint4*)vals + t);
        insert_one_atomic((uint32_t)v.x, bits);
        insert_one_atomic((uint32_t)v.y, bits);
        insert_one_atomic((uint32_t)v.z, bits);
        insert_one_atomic((uint32_t)v.w, bits);
    } else {
        for (int j = base; j < n; ++j) insert_one_atomic((uint32_t)vals[j], bits);
    }
}

__global__ __launch_bounds__(256) void build_h_kernel(
    const unsigned long long* __restrict__ bits, unsigned long long* __restrict__ H)
{
    uint32_t i = blockIdx.x * 256 + threadIdx.x;        // [0, 2^19), grid exact
    const vull2* b2 = (const vull2*)bits + (size_t)i * 2;
    vull2 a = b2[0];
    vull2 b = b2[1];
    unsigned long long hw = nib16(a[0])
                          | (nib16(a[1]) << 16)
                          | (nib16(b[0]) << 32)
                          | (nib16(b[1]) << 48);
    H[i] = hw;
}

__global__ __launch_bounds__(256) void query_kernel8(
    const int* __restrict__ vals, int n,
    const unsigned long long* __restrict__ bits, int* __restrict__ out)
{
    int t = blockIdx.x * 256 + threadIdx.x;
    int base = t * 8;
    if (base + 7 < n) {
        vint4 v0 = __builtin_nontemporal_load((const vint4*)(vals + base));
        vint4 v1 = __builtin_nontemporal_load((const vint4*)(vals + base + 4));
        vint4 r0, r1;
        #pragma unroll
        for (int j = 0; j < 8; ++j) {
            uint32_t v = (uint32_t)(j < 4 ? v0[j] : v1[j - 4]);
            int r = query_one_branchy(v, bits);
            if (j < 4) r0[j] = r; else r1[j - 4] = r;
        }
        __builtin_nontemporal_store(r0, (vint4*)(out + base));
        __builtin_nontemporal_store(r1, (vint4*)(out + base + 4));
    } else {
        for (int j = base; j < n; ++j)
            out[j] = query_one_branchy((uint32_t)vals[j], bits);
    }
}

extern "C" void kernel_launch(void* const* d_in, const int* in_sizes, int n_in,
                              void* d_out, int out_size, void* d_ws, size_t ws_size,
                              hipStream_t stream) {
    const int* add_values   = (const int*)d_in[0];
    const int* query_values = (const int*)d_in[1];
    const int n_add   = in_sizes[0];   // 4,000,000
    const int n_query = in_sizes[1];   // 8,000,000
    int* out = (int*)d_out;

    uint8_t* ws = (uint8_t*)d_ws;
    unsigned long long* bits = (unsigned long long*)ws;
    unsigned long long* H    = (unsigned long long*)(ws + 16777216);
    uint32_t* lists = (uint32_t*)(ws + 20971520);
    uint32_t* gcnt  = (uint32_t*)(ws + 38764544);

    const int threads8 = (n_query + 7) / 8;

    if (ws_size >= WS_FULL) {
        const uint32_t nchunks = ((uint32_t)n_add + CHUNK - 1u) / CHUNK;
        hipMemsetAsync(gcnt, 0, NBUCKETS * sizeof(uint32_t), stream);
        scatter_kernel<<<nchunks, 512, 0, stream>>>(add_values, n_add, lists, gcnt);
        build_bitmap_kernel<<<NBUCKETS, 1024, 0, stream>>>(lists, gcnt, bits, H);
        query_kernelH<<<(threads8 + 255) / 256, 256, 0, stream>>>(
            query_values, n_query, bits, (const uint32_t*)H, out);
    } else if (ws_size >= WS_H_ONLY) {
        const int n2 = NUM_WORDS / 2;
        zero_bits_kernel<<<(n2 + 255) / 256, 256, 0, stream>>>((vull2*)bits, n2);
        const int threads4 = (n_add + 3) / 4;
        insert_atomic_kernel<<<(threads4 + 255) / 256, 256, 0, stream>>>(
            add_values, n_add, bits);
        build_h_kernel<<<H_WORDS / 256, 256, 0, stream>>>(bits, H);
        query_kernelH<<<(threads8 + 255) / 256, 256, 0, stream>>>(
            query_values, n_query, bits, (const uint32_t*)H, out);
    } else {
        const int n2 = NUM_WORDS / 2;
        zero_bits_kernel<<<(n2 + 255) / 256, 256, 0, stream>>>((vull2*)bits, n2);
        const int threads4 = (n_add + 3) / 4;
        insert_atomic_kernel<<<(threads4 + 255) / 256, 256, 0, stream>>>(
            add_values, n_add, bits);
        query_kernel8<<<(threads8 + 255) / 256, 256, 0, stream>>>(
            query_values, n_query, bits, out);
    }
}